// Round 6
// baseline (453.214 us; speedup 1.0000x reference)
//
#include <hip/hip_runtime.h>
#include <hip/hip_bf16.h>

typedef __attribute__((ext_vector_type(4))) float f32x4;
typedef __attribute__((ext_vector_type(8))) short bf16x8;

#define NN 131072      // minibatch nodes
#define TT 100000      // rows per featured type table
#define DD 512         // raw feature dim
#define EE 256         // embedding size
#define GEMM_REPS 8    // PROFILING: repeat GEMM body to surface it in rocprof top-5

__device__ inline ushort f2bf(float f) {
    union { float f; unsigned u; } x; x.f = f;
    unsigned r = x.u + 0x7fffu + ((x.u >> 16) & 1u);
    return (ushort)(r >> 16);
}

// ---------------- prep: W (D x E, f32) -> Wt (E x D, bf16); also zero cnt ----
__global__ void prep_w_kernel(const float* __restrict__ W0, const float* __restrict__ W1,
                              ushort* __restrict__ Wt0, ushort* __restrict__ Wt1,
                              int* __restrict__ cnt) {
    if (blockIdx.x == 0 && threadIdx.x < 4) cnt[threadIdx.x] = 0;
    int gid = blockIdx.x * 256 + threadIdx.x;   // 65536 total = 2 * 512 * 64
    int t = gid >> 15;
    int rem = gid & 32767;
    int d = rem >> 6, eg = rem & 63;
    const float* W = t ? W1 : W0;
    ushort* Wt = t ? Wt1 : Wt0;
    f32x4 v = *(const f32x4*)(W + d * EE + eg * 4);
#pragma unroll
    for (int j = 0; j < 4; ++j)
        Wt[(size_t)(eg * 4 + j) * DD + d] = f2bf(v[j]);
}

// ---------------- compact: ballot+popc, one atomic per block per type --------
__global__ void compact_kernel(const int* __restrict__ tids, int* __restrict__ cnt,
                               int* __restrict__ l0, int* __restrict__ l1) {
    const int i = blockIdx.x * 256 + threadIdx.x;   // grid exact: 512*256 = NN
    const int t = tids[i];
    const int lane = threadIdx.x & 63, wid = threadIdx.x >> 6;
    unsigned long long b0 = __ballot(t == 0);
    unsigned long long b1 = __ballot(t == 1);
    __shared__ int w0[4], w1[4];
    __shared__ int base0, base1;
    if (lane == 0) { w0[wid] = __popcll(b0); w1[wid] = __popcll(b1); }
    __syncthreads();
    if (threadIdx.x == 0) {
        base0 = atomicAdd(&cnt[0], w0[0] + w0[1] + w0[2] + w0[3]);
        base1 = atomicAdd(&cnt[1], w1[0] + w1[1] + w1[2] + w1[3]);
    }
    __syncthreads();
    int p0 = 0, p1 = 0;
#pragma unroll
    for (int w = 0; w < 4; ++w) if (w < wid) { p0 += w0[w]; p1 += w1[w]; }
    const unsigned long long ltm = (1ull << lane) - 1ull;
    if (t == 0)      l0[base0 + p0 + __popcll(b0 & ltm)] = i;
    else if (t == 1) l1[base1 + p1 + __popcll(b1 & ltm)] = i;
}

// ---------------- embedding gather for tids >= 2 ----------------
__global__ void emb_gather_kernel(const int* __restrict__ ids, const int* __restrict__ tids,
                                  const float* __restrict__ emb, float* __restrict__ out) {
    int gid = blockIdx.x * 256 + threadIdx.x;   // N*64 total, float4 granularity
    int i = gid >> 6, j = gid & 63;
    if (tids[i] >= 2) {
        ((f32x4*)out)[(size_t)i * 64 + j] = ((const f32x4*)emb)[(size_t)ids[i] * 64 + j];
    }
}

// ---------------- fused gathered-A GEMM (R3 structure), x8 internal repeat ----
// out[list[r]] = bf16(feats[type_ids[list[r]]]) @ W. BM=128,BN=256,BK=64, 8 waves.
// PROFILING: body repeats GEMM_REPS times accumulating; epilogue scales by 1/8
// (exact in fp32). Result numerically ~identical; dispatch time ~8x so it
// surfaces above the harness 1GiB fills in rocprof top-5.
__global__ __launch_bounds__(512, 4) void gemm_gather_kernel(
    const int* __restrict__ l0, const int* __restrict__ l1,
    const int* __restrict__ cntp, const int* __restrict__ type_ids,
    const float* __restrict__ feats0, const float* __restrict__ feats1,
    const ushort* __restrict__ Wt0, const ushort* __restrict__ Wt1,
    float* __restrict__ out) {
    const int cnt0 = cntp[0], cnt1 = cntp[1];
    const int nt0 = (cnt0 + 127) >> 7;
    const int nt1 = (cnt1 + 127) >> 7;
    const int b = blockIdx.x;
    const int* list; const float* feats; const ushort* Wt; int cnt, tile;
    if (b < nt0)                { tile = b;          list = l0; feats = feats0; Wt = Wt0; cnt = cnt0; }
    else if (b < nt0 + nt1)  { tile = b - nt0; list = l1; feats = feats1; Wt = Wt1; cnt = cnt1; }
    else return;
    const int row0 = tile * 128;

    __shared__ char Alds[128 * 64 * 2];   // 16 KB, byte addr row*128 + k*2, XOR swizzled
    __shared__ char Blds[256 * 64 * 2];   // 32 KB, byte addr col*128 + k*2, XOR swizzled

    const int tid = threadIdx.x;
    const int lane = tid & 63, wid = tid >> 6;
    const int wr = wid >> 1, wc = wid & 1;      // wave tile: 32 rows x 128 cols
    const int ln15 = lane & 15, lq = lane >> 4;

    // A gather: thread = (row = tid>>2) x (seg = tid&3, 16 f32 each)
    const int ar = tid >> 2, aseg = tid & 3;
    const int rg = row0 + ar;
    int arow = 0;
    if (rg < cnt) arow = type_ids[list[rg]];
    const float* asrc = feats + (size_t)arow * DD + aseg * 16;
    int aw0 = ar * 128 + aseg * 32;
    int aw1 = aw0 + 16;
    aw0 ^= (ar & 7) << 4;
    aw1 ^= (ar & 7) << 4;

    f32x4 acc[2][8] = {};

    for (int rep = 0; rep < GEMM_REPS; ++rep) {
    for (int k0 = 0; k0 < DD; k0 += 64) {
        // ---- stage A: 16 f32 -> 16 bf16 -> 2x ds_write_b128
        const f32x4* ap = (const f32x4*)(asrc + k0);
        f32x4 v0 = ap[0], v1 = ap[1], v2 = ap[2], v3 = ap[3];
        bf16x8 h0, h1;
        h0[0] = (short)f2bf(v0[0]); h0[1] = (short)f2bf(v0[1]);
        h0[2] = (short)f2bf(v0[2]); h0[3] = (short)f2bf(v0[3]);
        h0[4] = (short)f2bf(v1[0]); h0[5] = (short)f2bf(v1[1]);
        h0[6] = (short)f2bf(v1[2]); h0[7] = (short)f2bf(v1[3]);
        h1[0] = (short)f2bf(v2[0]); h1[1] = (short)f2bf(v2[1]);
        h1[2] = (short)f2bf(v2[2]); h1[3] = (short)f2bf(v2[3]);
        h1[4] = (short)f2bf(v3[0]); h1[5] = (short)f2bf(v3[1]);
        h1[6] = (short)f2bf(v3[2]); h1[7] = (short)f2bf(v3[3]);
        *(bf16x8*)(Alds + aw0) = h0;
        *(bf16x8*)(Alds + aw1) = h1;

        // ---- stage B: 256 cols x 64 k bf16 from Wt (L2-resident)
#pragma unroll
        for (int p = 0; p < 4; ++p) {
            int c = p * 512 + tid;
            int col = c >> 3, seg = c & 7;
            bf16x8 bv = *(const bf16x8*)(Wt + col * DD + k0 + seg * 8);
            int addr = col * 128 + seg * 16;
            addr ^= (col & 7) << 4;
            *(bf16x8*)(Blds + addr) = bv;
        }
        __syncthreads();

        // ---- compute: 2 k-halves x (2 M-frags x 8 N-frags)
#pragma unroll
        for (int kh = 0; kh < 2; ++kh) {
            const int kb = kh * 64 + lq * 16;
            int ra0 = wr * 32 + ln15;
            int a0addr = (ra0 * 128 + kb) ^ ((ra0 & 7) << 4);
            int ra1 = ra0 + 16;
            int a1addr = (ra1 * 128 + kb) ^ ((ra1 & 7) << 4);
            bf16x8 a0 = *(const bf16x8*)(Alds + a0addr);
            bf16x8 a1 = *(const bf16x8*)(Alds + a1addr);
#pragma unroll
            for (int ni = 0; ni < 8; ++ni) {
                int col = wc * 128 + ni * 16 + ln15;
                int baddr = (col * 128 + kb) ^ ((col & 7) << 4);
                bf16x8 bfr = *(const bf16x8*)(Blds + baddr);
                acc[0][ni] = __builtin_amdgcn_mfma_f32_16x16x32_bf16(a0, bfr, acc[0][ni], 0, 0, 0);
                acc[1][ni] = __builtin_amdgcn_mfma_f32_16x16x32_bf16(a1, bfr, acc[1][ni], 0, 0, 0);
            }
        }
        __syncthreads();
    }
    }  // rep

    // ---- epilogue: scatter rows to out[node], scale by 1/GEMM_REPS (exact)
#pragma unroll
    for (int mi = 0; mi < 2; ++mi) {
        int mbase = row0 + wr * 32 + mi * 16 + lq * 4;
#pragma unroll
        for (int rr = 0; rr < 4; ++rr) {
            int r = mbase + rr;
            if (r < cnt) {
                int nd = list[r];
                float* orow = out + (size_t)nd * EE + wc * 128 + ln15;
#pragma unroll
                for (int ni = 0; ni < 8; ++ni) orow[ni * 16] = acc[mi][ni][rr] * 0.125f;
            }
        }
    }
}

extern "C" void kernel_launch(void* const* d_in, const int* in_sizes, int n_in,
                              void* d_out, int out_size, void* d_ws, size_t ws_size,
                              hipStream_t stream) {
    const int*   node_ids  = (const int*)d_in[0];
    const int*   node_tids = (const int*)d_in[1];
    const int*   type_ids  = (const int*)d_in[2];
    const float* feats0    = (const float*)d_in[3];
    const float* feats1    = (const float*)d_in[4];
    const float* W0        = (const float*)d_in[5];
    const float* W1        = (const float*)d_in[6];
    const float* node_emb  = (const float*)d_in[7];
    float* out = (float*)d_out;

    char* ws = (char*)d_ws;
    int* cnt = (int*)ws;                              // 16 B
    int* l0  = (int*)(ws + 16);                       // N ints
    int* l1  = (int*)(ws + 16 + 524288);              // N ints
    ushort* Wt0 = (ushort*)(ws + 16 + 2 * 524288);    // 256 KB
    ushort* Wt1 = Wt0 + DD * EE;                      // 256 KB

    prep_w_kernel<<<256, 256, 0, stream>>>(W0, W1, Wt0, Wt1, cnt);
    compact_kernel<<<512, 256, 0, stream>>>(node_tids, cnt, l0, l1);
    emb_gather_kernel<<<32768, 256, 0, stream>>>(node_ids, node_tids, node_emb, out);
    gemm_gather_kernel<<<2048, 512, 0, stream>>>(l0, l1, cnt, type_ids,
                                                 feats0, feats1, Wt0, Wt1, out);
}

// Round 7
// 189.814 us; speedup vs baseline: 2.3877x; 2.3877x over previous
//
#include <hip/hip_runtime.h>
#include <hip/hip_bf16.h>

typedef __attribute__((ext_vector_type(4))) float f32x4;
typedef __attribute__((ext_vector_type(8))) short bf16x8;

#define NN 131072      // minibatch nodes
#define TT 100000      // rows per featured type table
#define DD 512         // raw feature dim
#define EE 256         // embedding size
#define NT_MAX 1026    // worst-case fused tiles at 128 rows/block

__device__ inline ushort f2bf(float f) {
    union { float f; unsigned u; } x; x.f = f;
    unsigned r = x.u + 0x7fffu + ((x.u >> 16) & 1u);
    return (ushort)(r >> 16);
}

// ---------------- prep: W (D x E, f32) -> Wt (E x D, bf16); also zero cnt ----
__global__ void prep_w_kernel(const float* __restrict__ W0, const float* __restrict__ W1,
                              ushort* __restrict__ Wt0, ushort* __restrict__ Wt1,
                              int* __restrict__ cnt) {
    if (blockIdx.x == 0 && threadIdx.x < 4) cnt[threadIdx.x] = 0;
    int gid = blockIdx.x * 256 + threadIdx.x;   // 65536 total = 2 * 512 * 64
    int t = gid >> 15;
    int rem = gid & 32767;
    int d = rem >> 6, eg = rem & 63;
    const float* W = t ? W1 : W0;
    ushort* Wt = t ? Wt1 : Wt0;
    f32x4 v = *(const f32x4*)(W + d * EE + eg * 4);
#pragma unroll
    for (int j = 0; j < 4; ++j)
        Wt[(size_t)(eg * 4 + j) * DD + d] = f2bf(v[j]);
}

// ---------------- compact: ballot+popc, one atomic per block per type --------
__global__ void compact_kernel(const int* __restrict__ tids, int* __restrict__ cnt,
                               int* __restrict__ l0, int* __restrict__ l1) {
    const int i = blockIdx.x * 256 + threadIdx.x;   // grid exact: 512*256 = NN
    const int t = tids[i];
    const int lane = threadIdx.x & 63, wid = threadIdx.x >> 6;
    unsigned long long b0 = __ballot(t == 0);
    unsigned long long b1 = __ballot(t == 1);
    __shared__ int w0[4], w1[4];
    __shared__ int base0, base1;
    if (lane == 0) { w0[wid] = __popcll(b0); w1[wid] = __popcll(b1); }
    __syncthreads();
    if (threadIdx.x == 0) {
        base0 = atomicAdd(&cnt[0], w0[0] + w0[1] + w0[2] + w0[3]);
        base1 = atomicAdd(&cnt[1], w1[0] + w1[1] + w1[2] + w1[3]);
    }
    __syncthreads();
    int p0 = 0, p1 = 0;
#pragma unroll
    for (int w = 0; w < 4; ++w) if (w < wid) { p0 += w0[w]; p1 += w1[w]; }
    const unsigned long long ltm = (1ull << lane) - 1ull;
    if (t == 0)      l0[base0 + p0 + __popcll(b0 & ltm)] = i;
    else if (t == 1) l1[base1 + p1 + __popcll(b1 & ltm)] = i;
}

// ---------------- embedding gather for tids >= 2 ----------------
__global__ void emb_gather_kernel(const int* __restrict__ ids, const int* __restrict__ tids,
                                  const float* __restrict__ emb, float* __restrict__ out) {
    int gid = blockIdx.x * 256 + threadIdx.x;   // N*64 total, float4 granularity
    int i = gid >> 6, j = gid & 63;
    if (tids[i] >= 2) {
        ((f32x4*)out)[(size_t)i * 64 + j] = ((const f32x4*)emb)[(size_t)ids[i] * 64 + j];
    }
}

// ---------------- barrier-free wave-autonomous gathered GEMM -----------------
// out[list[r]] = bf16(feats[type_ids[list[r]]]) @ W.
// Each wave owns 32 rows x 256 cols: A-frags loaded straight from feats in MFMA
// lane layout (f32 -> bf16 in reg), B-frags straight from Wt (L2-resident).
// NO LDS, NO barriers -> waves free-run, loads pipeline across K iterations.
__global__ __launch_bounds__(256, 2) void gemm_gather_kernel(
    const int* __restrict__ l0, const int* __restrict__ l1,
    const int* __restrict__ cntp, const int* __restrict__ type_ids,
    const float* __restrict__ feats0, const float* __restrict__ feats1,
    const ushort* __restrict__ Wt0, const ushort* __restrict__ Wt1,
    float* __restrict__ out) {
    const int cnt0 = cntp[0], cnt1 = cntp[1];
    const int nt0 = (cnt0 + 127) >> 7;
    const int nt1 = (cnt1 + 127) >> 7;
    const int b = blockIdx.x;
    const int* list; const float* feats; const ushort* Wt; int cnt, tile;
    if (b < nt0)             { tile = b;       list = l0; feats = feats0; Wt = Wt0; cnt = cnt0; }
    else if (b < nt0 + nt1)  { tile = b - nt0; list = l1; feats = feats1; Wt = Wt1; cnt = cnt1; }
    else return;

    const int tid = threadIdx.x;
    const int lane = tid & 63, wid = tid >> 6;
    const int ln15 = lane & 15, lq = lane >> 4;
    const int base = tile * 128 + wid * 32;     // this wave's first row

    // this lane's two A rows (fragment rows base+ln15 and base+16+ln15)
    const int r0 = base + ln15, r1 = base + 16 + ln15;
    const int g0 = (r0 < cnt) ? type_ids[list[r0]] : 0;
    const int g1 = (r1 < cnt) ? type_ids[list[r1]] : 0;
    const float*  a0p = feats + (size_t)g0 * DD + lq * 8;   // lane's k-slice start
    const float*  a1p = feats + (size_t)g1 * DD + lq * 8;
    const ushort* bp  = Wt + (size_t)ln15 * DD + lq * 8;    // + ni*16*DD + kc

    f32x4 acc[2][16];
#pragma unroll
    for (int mi = 0; mi < 2; ++mi)
#pragma unroll
        for (int ni = 0; ni < 16; ++ni) acc[mi][ni] = f32x4{0.f, 0.f, 0.f, 0.f};

    for (int kc = 0; kc < DD; kc += 32) {
        // A: 8 f32 per row-frag -> bf16x8 (lane-layout = MFMA a-operand)
        f32x4 a0lo = *(const f32x4*)(a0p + kc), a0hi = *(const f32x4*)(a0p + kc + 4);
        f32x4 a1lo = *(const f32x4*)(a1p + kc), a1hi = *(const f32x4*)(a1p + kc + 4);
        bf16x8 A0, A1;
#pragma unroll
        for (int j = 0; j < 4; ++j) {
            A0[j]     = (short)f2bf(a0lo[j]);
            A0[j + 4] = (short)f2bf(a0hi[j]);
            A1[j]     = (short)f2bf(a1lo[j]);
            A1[j + 4] = (short)f2bf(a1hi[j]);
        }
#pragma unroll
        for (int ni = 0; ni < 16; ++ni) {
            bf16x8 Bf = *(const bf16x8*)(bp + ni * 16 * DD + kc);
            acc[0][ni] = __builtin_amdgcn_mfma_f32_16x16x32_bf16(A0, Bf, acc[0][ni], 0, 0, 0);
            acc[1][ni] = __builtin_amdgcn_mfma_f32_16x16x32_bf16(A1, Bf, acc[1][ni], 0, 0, 0);
        }
    }

    // epilogue: C row = lq*4 + j (+ mi*16), col = ni*16 + ln15; scatter to out[node]
#pragma unroll
    for (int mi = 0; mi < 2; ++mi) {
#pragma unroll
        for (int j = 0; j < 4; ++j) {
            const int r = base + mi * 16 + lq * 4 + j;
            if (r < cnt) {
                float* orow = out + (size_t)list[r] * EE + ln15;
#pragma unroll
                for (int ni = 0; ni < 16; ++ni) orow[ni * 16] = acc[mi][ni][j];
            }
        }
    }
}

extern "C" void kernel_launch(void* const* d_in, const int* in_sizes, int n_in,
                              void* d_out, int out_size, void* d_ws, size_t ws_size,
                              hipStream_t stream) {
    const int*   node_ids  = (const int*)d_in[0];
    const int*   node_tids = (const int*)d_in[1];
    const int*   type_ids  = (const int*)d_in[2];
    const float* feats0    = (const float*)d_in[3];
    const float* feats1    = (const float*)d_in[4];
    const float* W0        = (const float*)d_in[5];
    const float* W1        = (const float*)d_in[6];
    const float* node_emb  = (const float*)d_in[7];
    float* out = (float*)d_out;

    char* ws = (char*)d_ws;
    int* cnt = (int*)ws;                              // 16 B
    int* l0  = (int*)(ws + 16);                       // N ints
    int* l1  = (int*)(ws + 16 + 524288);              // N ints
    ushort* Wt0 = (ushort*)(ws + 16 + 2 * 524288);    // 256 KB
    ushort* Wt1 = Wt0 + DD * EE;                      // 256 KB

    prep_w_kernel<<<256, 256, 0, stream>>>(W0, W1, Wt0, Wt1, cnt);
    compact_kernel<<<512, 256, 0, stream>>>(node_tids, cnt, l0, l1);
    emb_gather_kernel<<<32768, 256, 0, stream>>>(node_ids, node_tids, node_emb, out);
    gemm_gather_kernel<<<NT_MAX, 256, 0, stream>>>(l0, l1, cnt, type_ids,
                                                   feats0, feats1, Wt0, Wt1, out);
}

// Round 8
// 166.835 us; speedup vs baseline: 2.7165x; 1.1377x over previous
//
#include <hip/hip_runtime.h>
#include <hip/hip_bf16.h>

typedef __attribute__((ext_vector_type(4))) float f32x4;
typedef __attribute__((ext_vector_type(8))) short bf16x8;

#define NN 131072      // minibatch nodes
#define TT 100000      // rows per featured type table
#define DD 512         // raw feature dim
#define EE 256         // embedding size
#define NT_MAX 1026    // worst-case GEMM tiles (128 rows each)

__device__ inline ushort f2bf(float f) {
    union { float f; unsigned u; } x; x.f = f;
    unsigned r = x.u + 0x7fffu + ((x.u >> 16) & 1u);
    return (ushort)(r >> 16);
}

__device__ inline void gload16(const void* g, void* l) {
    __builtin_amdgcn_global_load_lds(
        (const __attribute__((address_space(1))) unsigned int*)g,
        (__attribute__((address_space(3))) unsigned int*)l, 16, 0, 0);
}

// ---------------- prep: W (D x E, f32) -> Wt (E x D, bf16); also zero cnt ----
__global__ void prep_w_kernel(const float* __restrict__ W0, const float* __restrict__ W1,
                              ushort* __restrict__ Wt0, ushort* __restrict__ Wt1,
                              int* __restrict__ cnt) {
    if (blockIdx.x == 0 && threadIdx.x < 4) cnt[threadIdx.x] = 0;
    int gid = blockIdx.x * 256 + threadIdx.x;   // 65536 total = 2 * 512 * 64
    int t = gid >> 15;
    int rem = gid & 32767;
    int d = rem >> 6, eg = rem & 63;
    const float* W = t ? W1 : W0;
    ushort* Wt = t ? Wt1 : Wt0;
    f32x4 v = *(const f32x4*)(W + d * EE + eg * 4);
#pragma unroll
    for (int j = 0; j < 4; ++j)
        Wt[(size_t)(eg * 4 + j) * DD + d] = f2bf(v[j]);
}

// ---------------- gather_all: compact + A-copy(f32->bf16) + emb gather -------
// 2048 blocks x 256 threads, 64 nodes/block. Pure streaming, no MFMA coupling.
__global__ __launch_bounds__(256) void gather_all_kernel(
    const int* __restrict__ node_ids, const int* __restrict__ tids,
    const int* __restrict__ type_ids,
    const float* __restrict__ feats0, const float* __restrict__ feats1,
    const float* __restrict__ node_emb,
    int* __restrict__ cnt, int* __restrict__ l0, int* __restrict__ l1,
    ushort* __restrict__ Ac0, ushort* __restrict__ Ac1,
    float* __restrict__ out) {
    __shared__ int fsrc[64], frel[64], ftyp[64], erow[64], eidv[64];
    __shared__ int nfS, neS, b0S, b1S;
    const int tid = threadIdx.x;

    int my_t = -1, my_dstrel = 0, my_i = 0;
    if (tid < 64) {   // wave 0 compacts this block's 64 nodes
        const int i = blockIdx.x * 64 + tid;
        const int t = tids[i];
        unsigned long long b0 = __ballot(t == 0);
        unsigned long long b1 = __ballot(t == 1);
        unsigned long long b2 = __ballot(t >= 2);
        const unsigned long long ltm = (1ull << tid) - 1ull;
        const int n0 = __popcll(b0), n1 = __popcll(b1), n2 = __popcll(b2);
        if (tid == 0) {
            b0S = atomicAdd(&cnt[0], n0);
            b1S = atomicAdd(&cnt[1], n1);
            nfS = n0 + n1;
            neS = n2;
        }
        my_t = t; my_i = i;
        if (t == 0) {
            int idx = __popcll(b0 & ltm);
            my_dstrel = idx;
            fsrc[idx] = type_ids[i]; frel[idx] = idx; ftyp[idx] = 0;
        } else if (t == 1) {
            int idx = __popcll(b1 & ltm);
            my_dstrel = idx;
            fsrc[n0 + idx] = type_ids[i]; frel[n0 + idx] = idx; ftyp[n0 + idx] = 1;
        } else {
            int idx = __popcll(b2 & ltm);
            erow[idx] = i; eidv[idx] = node_ids[i];
        }
    }
    __syncthreads();
    const int base0 = b0S, base1 = b1S, nf = nfS, ne = neS;
    // wave 0 writes the scatter lists
    if (tid < 64) {
        if (my_t == 0)      l0[base0 + my_dstrel] = my_i;
        else if (my_t == 1) l1[base1 + my_dstrel] = my_i;
    }

    // featured rows: 4 rows/iter, 64 lanes/row, lane = 8 f32 -> 8 bf16
    const int sub = tid >> 6, ln = tid & 63;
    for (int g = 0; g < nf; g += 4) {
        int idx = g + sub;
        if (idx < nf) {
            int typ = ftyp[idx];
            int dst = frel[idx] + (typ ? base1 : base0);
            const float* s = (typ ? feats1 : feats0) + (size_t)fsrc[idx] * DD + ln * 8;
            f32x4 lo = *(const f32x4*)s, hi = *(const f32x4*)(s + 4);
            bf16x8 h;
#pragma unroll
            for (int j = 0; j < 4; ++j) {
                h[j]     = (short)f2bf(lo[j]);
                h[j + 4] = (short)f2bf(hi[j]);
            }
            *(bf16x8*)((typ ? Ac1 : Ac0) + (size_t)dst * DD + ln * 8) = h;
        }
    }
    // emb rows: 4 rows/iter, 64 lanes x f32x4
    for (int g = 0; g < ne; g += 4) {
        int idx = g + sub;
        if (idx < ne) {
            ((f32x4*)out)[(size_t)erow[idx] * 64 + ln] =
                ((const f32x4*)node_emb)[(size_t)eidv[idx] * 64 + ln];
        }
    }
}

// ---------------- dense GEMM from compacted A (m97-style gload_lds) ----------
// out[list[r]] = Acomp[r] @ W.  BM=128, BN=256, BK=64, 512 thr = 8 waves (4Mx2N).
// global_load_lds w=16 both operands; pre-swizzled source + linear dest +
// swizzled ds_read (phys = row*128 + (seg^(row&7))*16).
__global__ __launch_bounds__(512, 4) void gemm_dense_kernel(
    const int* __restrict__ l0, const int* __restrict__ l1,
    const int* __restrict__ cntp,
    const ushort* __restrict__ Ac0, const ushort* __restrict__ Ac1,
    const ushort* __restrict__ Wt0, const ushort* __restrict__ Wt1,
    float* __restrict__ out) {
    const int cnt0 = cntp[0], cnt1 = cntp[1];
    const int nt0 = (cnt0 + 127) >> 7;
    const int nt1 = (cnt1 + 127) >> 7;
    const int b = blockIdx.x;
    const int* list; const ushort* Ac; const ushort* Wt; int cnt, tile;
    if (b < nt0)             { tile = b;       list = l0; Ac = Ac0; Wt = Wt0; cnt = cnt0; }
    else if (b < nt0 + nt1)  { tile = b - nt0; list = l1; Ac = Ac1; Wt = Wt1; cnt = cnt1; }
    else return;
    const int row0 = tile * 128;

    __shared__ char Alds[128 * 64 * 2];   // 16 KB
    __shared__ char Blds[256 * 64 * 2];   // 32 KB

    const int tid = threadIdx.x;
    const int lane = tid & 63, wid = tid >> 6;
    const int wr = wid >> 1, wc = wid & 1;      // wave tile: 32 rows x 128 cols
    const int ln15 = lane & 15, lq = lane >> 4;

    // staging source addresses (pre-swizzled so linear gload dest = swizzled layout)
    // dest byte d = p*8192 + tid*16 ; row = d>>7 ; sphys = (d>>4)&7 ; seg = sphys^(row&7)
    int arowA[2], asegA[2];
#pragma unroll
    for (int p = 0; p < 2; ++p) {
        int d = p * 8192 + tid * 16;
        arowA[p] = d >> 7;
        asegA[p] = ((d >> 4) & 7) ^ (arowA[p] & 7);
    }
    int bcolB[4], bsegB[4];
#pragma unroll
    for (int p = 0; p < 4; ++p) {
        int d = p * 8192 + tid * 16;
        bcolB[p] = d >> 7;
        bsegB[p] = ((d >> 4) & 7) ^ (bcolB[p] & 7);
    }

    f32x4 acc[2][8] = {};

    for (int k0 = 0; k0 < DD; k0 += 64) {
        // ---- stage A (2 issues) + B (4 issues), direct-to-LDS
#pragma unroll
        for (int p = 0; p < 2; ++p)
            gload16(Ac + (size_t)(row0 + arowA[p]) * DD + k0 + asegA[p] * 8,
                    Alds + p * 8192 + wid * 1024);
#pragma unroll
        for (int p = 0; p < 4; ++p)
            gload16(Wt + (size_t)bcolB[p] * DD + k0 + bsegB[p] * 8,
                    Blds + p * 8192 + wid * 1024);
        __syncthreads();

        // ---- compute: 2 k-halves x (2 M-frags x 8 N-frags)
#pragma unroll
        for (int kh = 0; kh < 2; ++kh) {
            const int kb = kh * 64 + lq * 16;
            int ra0 = wr * 32 + ln15;
            int a0addr = (ra0 * 128 + kb) ^ ((ra0 & 7) << 4);
            int ra1 = ra0 + 16;
            int a1addr = (ra1 * 128 + kb) ^ ((ra1 & 7) << 4);
            bf16x8 a0 = *(const bf16x8*)(Alds + a0addr);
            bf16x8 a1 = *(const bf16x8*)(Alds + a1addr);
#pragma unroll
            for (int ni = 0; ni < 8; ++ni) {
                int col = wc * 128 + ni * 16 + ln15;
                int baddr = (col * 128 + kb) ^ ((col & 7) << 4);
                bf16x8 bfr = *(const bf16x8*)(Blds + baddr);
                acc[0][ni] = __builtin_amdgcn_mfma_f32_16x16x32_bf16(a0, bfr, acc[0][ni], 0, 0, 0);
                acc[1][ni] = __builtin_amdgcn_mfma_f32_16x16x32_bf16(a1, bfr, acc[1][ni], 0, 0, 0);
            }
        }
        __syncthreads();
    }

    // ---- epilogue: scatter rows to out[node]
#pragma unroll
    for (int mi = 0; mi < 2; ++mi) {
        int mbase = row0 + wr * 32 + mi * 16 + lq * 4;
#pragma unroll
        for (int rr = 0; rr < 4; ++rr) {
            int r = mbase + rr;
            if (r < cnt) {
                int nd = list[r];
                float* orow = out + (size_t)nd * EE + wc * 128 + ln15;
#pragma unroll
                for (int ni = 0; ni < 8; ++ni) orow[ni * 16] = acc[mi][ni][rr];
            }
        }
    }
}

extern "C" void kernel_launch(void* const* d_in, const int* in_sizes, int n_in,
                              void* d_out, int out_size, void* d_ws, size_t ws_size,
                              hipStream_t stream) {
    const int*   node_ids  = (const int*)d_in[0];
    const int*   node_tids = (const int*)d_in[1];
    const int*   type_ids  = (const int*)d_in[2];
    const float* feats0    = (const float*)d_in[3];
    const float* feats1    = (const float*)d_in[4];
    const float* W0        = (const float*)d_in[5];
    const float* W1        = (const float*)d_in[6];
    const float* node_emb  = (const float*)d_in[7];
    float* out = (float*)d_out;

    char* ws = (char*)d_ws;
    int* cnt = (int*)ws;                              // 16 B
    int* l0  = (int*)(ws + 16);                       // N ints (512 KB)
    int* l1  = (int*)(ws + 16 + 524288);              // N ints
    ushort* Wt0 = (ushort*)(ws + 16 + 2 * 524288);    // 256 KB
    ushort* Wt1 = Wt0 + DD * EE;                      // 256 KB
    // compacted A: worst case N rows each + 128-row tile pad
    ushort* Ac0 = (ushort*)(ws + 16 + 2 * 524288 + 2 * 262144);
    ushort* Ac1 = Ac0 + (size_t)(NN + 128) * DD;

    prep_w_kernel<<<256, 256, 0, stream>>>(W0, W1, Wt0, Wt1, cnt);
    gather_all_kernel<<<2048, 256, 0, stream>>>(node_ids, node_tids, type_ids,
                                                feats0, feats1, node_emb,
                                                cnt, l0, l1, Ac0, Ac1, out);
    gemm_dense_kernel<<<NT_MAX, 512, 0, stream>>>(l0, l1, cnt, Ac0, Ac1,
                                                  Wt0, Wt1, out);
}

// Round 9
// 133.324 us; speedup vs baseline: 3.3993x; 1.2514x over previous
//
#include <hip/hip_runtime.h>
#include <hip/hip_bf16.h>

typedef __attribute__((ext_vector_type(4))) float f32x4;
typedef __attribute__((ext_vector_type(8))) short bf16x8;

#define NN 131072      // minibatch nodes
#define TT 100000      // rows per featured type table
#define DD 512         // raw feature dim
#define EE 256         // embedding size
#define NT_MAX 1026    // worst-case GEMM tiles (128 rows each)

__device__ inline ushort f2bf(float f) {
    union { float f; unsigned u; } x; x.f = f;
    unsigned r = x.u + 0x7fffu + ((x.u >> 16) & 1u);
    return (ushort)(r >> 16);
}

__device__ inline void gload16(const void* g, void* l) {
    __builtin_amdgcn_global_load_lds(
        (const __attribute__((address_space(1))) unsigned int*)g,
        (__attribute__((address_space(3))) unsigned int*)l, 16, 0, 0);
}

// ---------------- prep: W (D x E, f32) -> Wt (E x D, bf16); also zero cnt ----
__global__ void prep_w_kernel(const float* __restrict__ W0, const float* __restrict__ W1,
                              ushort* __restrict__ Wt0, ushort* __restrict__ Wt1,
                              int* __restrict__ cnt) {
    if (blockIdx.x == 0 && threadIdx.x < 4) cnt[threadIdx.x] = 0;
    int gid = blockIdx.x * 256 + threadIdx.x;   // 65536 total = 2 * 512 * 64
    int t = gid >> 15;
    int rem = gid & 32767;
    int d = rem >> 6, eg = rem & 63;
    const float* W = t ? W1 : W0;
    ushort* Wt = t ? Wt1 : Wt0;
    f32x4 v = *(const f32x4*)(W + d * EE + eg * 4);
#pragma unroll
    for (int j = 0; j < 4; ++j)
        Wt[(size_t)(eg * 4 + j) * DD + d] = f2bf(v[j]);
}

// ---------------- compact: ballot+popc, one atomic per block per type --------
__global__ void compact_kernel(const int* __restrict__ tids, int* __restrict__ cnt,
                               int* __restrict__ l0, int* __restrict__ l1) {
    const int i = blockIdx.x * 256 + threadIdx.x;   // grid exact: 512*256 = NN
    const int t = tids[i];
    const int lane = threadIdx.x & 63, wid = threadIdx.x >> 6;
    unsigned long long b0 = __ballot(t == 0);
    unsigned long long b1 = __ballot(t == 1);
    __shared__ int w0[4], w1[4];
    __shared__ int base0, base1;
    if (lane == 0) { w0[wid] = __popcll(b0); w1[wid] = __popcll(b1); }
    __syncthreads();
    if (threadIdx.x == 0) {
        base0 = atomicAdd(&cnt[0], w0[0] + w0[1] + w0[2] + w0[3]);
        base1 = atomicAdd(&cnt[1], w1[0] + w1[1] + w1[2] + w1[3]);
    }
    __syncthreads();
    int p0 = 0, p1 = 0;
#pragma unroll
    for (int w = 0; w < 4; ++w) if (w < wid) { p0 += w0[w]; p1 += w1[w]; }
    const unsigned long long ltm = (1ull << lane) - 1ull;
    if (t == 0)      l0[base0 + p0 + __popcll(b0 & ltm)] = i;
    else if (t == 1) l1[base1 + p1 + __popcll(b1 & ltm)] = i;
}

// ---------------- embedding gather for tids >= 2 (wave = 1 full row) ---------
__global__ void emb_gather_kernel(const int* __restrict__ ids, const int* __restrict__ tids,
                                  const float* __restrict__ emb, float* __restrict__ out) {
    int gid = blockIdx.x * 256 + threadIdx.x;   // N*64 total, float4 granularity
    int i = gid >> 6, j = gid & 63;
    if (tids[i] >= 2) {
        ((f32x4*)out)[(size_t)i * 64 + j] = ((const f32x4*)emb)[(size_t)ids[i] * 64 + j];
    }
}

// ---------------- fused gathered-A GEMM, 2-phase gload_lds double-buffer -----
// out[list[r]] = bf16(feats[type_ids[list[r]]]) @ W. BM=128,BN=256,BK=64, 8 waves.
// A staged as f32 direct-to-LDS (gathered per-lane src, inverse-swizzled);
// B staged as bf16 direct-to-LDS. Stage(k+1) issued BEFORE compute(k); the
// single __syncthreads per K-step drains vmcnt after a full compute of cover.
__global__ __launch_bounds__(512, 4) void gemm_gather_kernel(
    const int* __restrict__ l0, const int* __restrict__ l1,
    const int* __restrict__ cntp, const int* __restrict__ type_ids,
    const float* __restrict__ feats0, const float* __restrict__ feats1,
    const ushort* __restrict__ Wt0, const ushort* __restrict__ Wt1,
    float* __restrict__ out) {
    const int cnt0 = cntp[0], cnt1 = cntp[1];
    const int nt0 = (cnt0 + 127) >> 7;
    const int nt1 = (cnt1 + 127) >> 7;
    const int b = blockIdx.x;
    const int* list; const float* feats; const ushort* Wt; int cnt, tile;
    if (b < nt0)             { tile = b;       list = l0; feats = feats0; Wt = Wt0; cnt = cnt0; }
    else if (b < nt0 + nt1)  { tile = b - nt0; list = l1; feats = feats1; Wt = Wt1; cnt = cnt1; }
    else return;
    const int row0 = tile * 128;

    // A: f32, phys = row*256 + ((chunk ^ (row&7))*32) + off  (chunk = 32B granule)
    // B: bf16, phys = col*128 + ((seg ^ (col&7))*16)         (seg = 16B granule)
    __shared__ char Alds[2][32768];
    __shared__ char Blds[2][32768];

    const int tid = threadIdx.x;
    const int lane = tid & 63, wid = tid >> 6;
    const int wr = wid >> 1, wc = wid & 1;      // wave tile: 32 rows x 128 cols
    const int ln15 = lane & 15, lq = lane >> 4;

    // ---- staging sources (per-lane, inverse-swizzled; +k0 walks K) ----
    // A dest byte d = p*8192 + tid*16 -> row = p*32 + (tid>>4),
    //   pchunk = (tid>>1)&7, half = tid&1; logical chunk = pchunk ^ (row&7)
    const float* asrc[4];
#pragma unroll
    for (int p = 0; p < 4; ++p) {
        int rp = p * 32 + (tid >> 4);
        int rg = row0 + rp;
        int g = (rg < cnt) ? type_ids[list[rg]] : 0;
        int lchunk = ((tid >> 1) & 7) ^ (rp & 7);
        asrc[p] = feats + (size_t)g * DD + lchunk * 8 + (tid & 1) * 4;
    }
    // B dest byte d = p*8192 + tid*16 -> col = d>>7, seg = ((d>>4)&7) ^ (col&7)
    const ushort* bsrc[4];
#pragma unroll
    for (int p = 0; p < 4; ++p) {
        int d = p * 8192 + tid * 16;
        int col = d >> 7;
        int seg = ((d >> 4) & 7) ^ (col & 7);
        bsrc[p] = Wt + (size_t)col * DD + seg * 8;
    }

    auto stage = [&](int buf, int k0) {
#pragma unroll
        for (int p = 0; p < 4; ++p)
            gload16(asrc[p] + k0, &Alds[buf][p * 8192 + wid * 1024]);
#pragma unroll
        for (int p = 0; p < 4; ++p)
            gload16(bsrc[p] + k0, &Blds[buf][p * 8192 + wid * 1024]);
    };

    f32x4 acc[2][8] = {};

    stage(0, 0);
    __syncthreads();

    for (int kk = 0; kk < 8; ++kk) {
        const int cur = kk & 1;
        if (kk < 7) stage(cur ^ 1, (kk + 1) * 64);   // fire-and-forget prefetch

        // ---- compute from Alds[cur] / Blds[cur]
#pragma unroll
        for (int kh = 0; kh < 2; ++kh) {
            const int kb = kh * 64 + lq * 16;        // B 16B-seg byte offset
            const int ch = kh * 4 + lq;              // A 32B-chunk index
            const int ra0 = wr * 32 + ln15;
            const int ra1 = ra0 + 16;
            const char* a0p = &Alds[cur][ra0 * 256 + ((ch ^ (ra0 & 7)) << 5)];
            const char* a1p = &Alds[cur][ra1 * 256 + ((ch ^ (ra1 & 7)) << 5)];
            f32x4 a0lo = *(const f32x4*)a0p, a0hi = *(const f32x4*)(a0p + 16);
            f32x4 a1lo = *(const f32x4*)a1p, a1hi = *(const f32x4*)(a1p + 16);
            bf16x8 A0, A1;
#pragma unroll
            for (int j = 0; j < 4; ++j) {
                A0[j]     = (short)f2bf(a0lo[j]);
                A0[j + 4] = (short)f2bf(a0hi[j]);
                A1[j]     = (short)f2bf(a1lo[j]);
                A1[j + 4] = (short)f2bf(a1hi[j]);
            }
#pragma unroll
            for (int ni = 0; ni < 8; ++ni) {
                int col = wc * 128 + ni * 16 + ln15;
                int baddr = (col * 128 + kb) ^ ((col & 7) << 4);
                bf16x8 bfr = *(const bf16x8*)(&Blds[cur][baddr]);
                acc[0][ni] = __builtin_amdgcn_mfma_f32_16x16x32_bf16(A0, bfr, acc[0][ni], 0, 0, 0);
                acc[1][ni] = __builtin_amdgcn_mfma_f32_16x16x32_bf16(A1, bfr, acc[1][ni], 0, 0, 0);
            }
        }
        __syncthreads();   // drains vmcnt (next buffer ready) + guards buffer reuse
    }

    // ---- epilogue: scatter rows to out[node]
#pragma unroll
    for (int mi = 0; mi < 2; ++mi) {
        int mbase = row0 + wr * 32 + mi * 16 + lq * 4;
#pragma unroll
        for (int rr = 0; rr < 4; ++rr) {
            int r = mbase + rr;
            if (r < cnt) {
                int nd = list[r];
                float* orow = out + (size_t)nd * EE + wc * 128 + ln15;
#pragma unroll
                for (int ni = 0; ni < 8; ++ni) orow[ni * 16] = acc[mi][ni][rr];
            }
        }
    }
}

extern "C" void kernel_launch(void* const* d_in, const int* in_sizes, int n_in,
                              void* d_out, int out_size, void* d_ws, size_t ws_size,
                              hipStream_t stream) {
    const int*   node_ids  = (const int*)d_in[0];
    const int*   node_tids = (const int*)d_in[1];
    const int*   type_ids  = (const int*)d_in[2];
    const float* feats0    = (const float*)d_in[3];
    const float* feats1    = (const float*)d_in[4];
    const float* W0        = (const float*)d_in[5];
    const float* W1        = (const float*)d_in[6];
    const float* node_emb  = (const float*)d_in[7];
    float* out = (float*)d_out;

    char* ws = (char*)d_ws;
    int* cnt = (int*)ws;                              // 16 B
    int* l0  = (int*)(ws + 16);                       // N ints
    int* l1  = (int*)(ws + 16 + 524288);              // N ints
    ushort* Wt0 = (ushort*)(ws + 16 + 2 * 524288);    // 256 KB
    ushort* Wt1 = Wt0 + DD * EE;                      // 256 KB

    prep_w_kernel<<<256, 256, 0, stream>>>(W0, W1, Wt0, Wt1, cnt);
    compact_kernel<<<512, 256, 0, stream>>>(node_tids, cnt, l0, l1);
    emb_gather_kernel<<<32768, 256, 0, stream>>>(node_ids, node_tids, node_emb, out);
    gemm_gather_kernel<<<NT_MAX, 512, 0, stream>>>(l0, l1, cnt, type_ids,
                                                   feats0, feats1, Wt0, Wt1, out);
}